// Round 9
// baseline (207.100 us; speedup 1.0000x reference)
//
#include <hip/hip_runtime.h>
#include <math.h>

// Problem constants
#define BN 256
#define TN 64
#define LN 32
#define DN 128
#define SN 4
#define HN 32   // column-panel width for the blocked elimination

#define LOG2PI 1.8378770664093453f

__device__ __forceinline__ float bcastf(float v, int lane) {
    return __builtin_bit_cast(float, __builtin_amdgcn_readlane(__builtin_bit_cast(int, v), lane));
}

// ===========================================================================
// Lessons R1-R8:
//  * All per-lane array subscripts must be frontend-time constants
//    (recursive if-constexpr templates) or SROA demotes to scratch.
//  * >64 live floats/lane -> AGPR parking (R5). 32-wide panels + dead-slot
//    multipliers keep peak ~50 -> 52 real VGPRs, zero scratch (R8).
//  * R8 residual: 32KB LDS -> 5 blocks/CU -> 36% occupancy -> readlane->fma
//    chains exposed (VALUBusy 62%). This round: 16KB LDS via 32-row
//    half-panel staging -> 8 blocks/CU (wave cap), grid = exactly 8/CU.
// ===========================================================================

// LDS plane layout: [32 rows][8 chunks][4 dwords]; chunk q of row i at
// position (q + i + (i>>3)) & 7 -> 8 consecutive lanes hit 8 distinct 16B
// slots (conflict-free b128 fills and staging stores).
__device__ __forceinline__ int chunk_pos(int q, int i) { return (q + i + (i >> 3)) & 7; }

// ---- shared template helpers ---------------------------------------------
template<int Q>
__device__ __forceinline__ void fillp(float (&r)[HN], const float* plane, int slot) {
    if constexpr (Q < 8) {
        const float4 v = *(const float4*)(plane + slot * 32 + chunk_pos(Q, slot) * 4);
        r[4 * Q + 0] = v.x; r[4 * Q + 1] = v.y;
        r[4 * Q + 2] = v.z; r[4 * Q + 3] = v.w;
        fillp<Q + 1>(r, plane, slot);
    }
}
template<int JBASE, int J4>
__device__ __forceinline__ void trace_half(const float (&r)[HN], const float* __restrict__ kp,
                                           float mu, float& tr, float& sm) {
    if constexpr (J4 < 8) {
        float4 kv = *(const float4*)(kp + 4 * J4);
        tr = fmaf(kv.x, r[4 * J4 + 0], tr); sm = fmaf(kv.x, bcastf(mu, JBASE + 4 * J4 + 0), sm);
        tr = fmaf(kv.y, r[4 * J4 + 1], tr); sm = fmaf(kv.y, bcastf(mu, JBASE + 4 * J4 + 1), sm);
        tr = fmaf(kv.z, r[4 * J4 + 2], tr); sm = fmaf(kv.z, bcastf(mu, JBASE + 4 * J4 + 2), sm);
        tr = fmaf(kv.w, r[4 * J4 + 3], tr); sm = fmaf(kv.w, bcastf(mu, JBASE + 4 * J4 + 3), sm);
        trace_half<JBASE, J4 + 1>(r, kp, mu, tr, sm);
    }
}

// ---- k_chol sweeps (register-resident multipliers, unchanged from R8) ----
template<int K, int J>
__device__ __forceinline__ void c1_upd(float (&r1)[HN], float c) {
    if constexpr (J < HN) {
        r1[J] = fmaf(-c, bcastf(r1[K], J), r1[J]);
        c1_upd<K, J + 1>(r1, c);
    }
}
template<int K>
__device__ __forceinline__ void c1_sweep(float (&r1)[HN], float& logdet) {
    if constexpr (K < HN) {
        float dkk = bcastf(r1[K], K);
        logdet += __logf(dkk);
        float c = r1[K] * __builtin_amdgcn_rcpf(dkk);
        c1_upd<K, K + 1>(r1, c);
        r1[K] = c;                          // multiplier -> dead slot
        c1_sweep<K + 1>(r1, logdet);
    }
}
template<int K, int J>
__device__ __forceinline__ void rep_upd(float (&r2)[HN], float c) {
    if constexpr (J < HN) {
        r2[J] = fmaf(-c, bcastf(r2[J], K), r2[J]);
        rep_upd<K, J + 1>(r2, c);
    }
}
template<int K>
__device__ __forceinline__ void rep_sweep(float (&r2)[HN], const float (&r1)[HN]) {
    if constexpr (K < HN) {
        rep_upd<K, 0>(r2, r1[K]);           // c from own stored multiplier
        rep_sweep<K + 1>(r2, r1);
    }
}
template<int Q, int J>
__device__ __forceinline__ void solo_upd(float (&r2)[HN], float c) {
    if constexpr (J < HN) {
        r2[J] = fmaf(-c, bcastf(r2[Q], 32 + J), r2[J]);
        solo_upd<Q, J + 1>(r2, c);
    }
}
template<int Q>
__device__ __forceinline__ void solo_sweep(float (&r2)[HN], float& logdet) {
    if constexpr (Q < HN) {
        float dkk = bcastf(r2[Q], 32 + Q);
        logdet += __logf(dkk);
        float c = r2[Q] * __builtin_amdgcn_rcpf(dkk);
        solo_upd<Q, Q + 1>(r2, c);
        solo_sweep<Q + 1>(r2, logdet);
    }
}

// ---------------------------------------------------------------------------
// Kernel: k_chol. Block = 256 threads = 4 waves = one (b, l-quad).
// LDS = 4 planes x 32x32 half-panel = 16 KB -> 8 blocks/CU (the 32-wave cap).
// Per panel: stage rows 0-31 -> lanes<32 fill; stage rows 32-63 -> lanes>=32
// fill. c1 compute sits between panels (no LDS use, r2 not yet live).
// ---------------------------------------------------------------------------
__global__ __launch_bounds__(256, 8)
void k_chol(const float* __restrict__ Sg,
            const float* __restrict__ mus,
            const float* __restrict__ kinv,
            const float* __restrict__ logdetK,
            float* __restrict__ out) {
    __shared__ float st[4 * 1024];       // 16 KB

    int hw = blockIdx.x;                 // 2048 blocks = 8 per CU, one round
    int g = (hw & 7) * 256 + (hw >> 3);  // XCD x owns b in [x*32, x*32+32)
    int b = g >> 3, lg = g & 7;          // lg = l-quad 0..7

    int tid = threadIdx.x;
    int w = tid >> 6, lane = tid & 63;   // wave w <-> l = lg*4 + w; lane = row
    int l = lg * 4 + w;
    int slot = lane & 31;                // row within the staged half

    float mu = mus[((size_t)b * TN + lane) * LN + l];
    const float* kp = kinv + l * (TN * TN) + lane * TN;
    const float* plane = &st[w * 1024];

    // stage a 32-row x 32-col half-panel (rows r0..r0+31, cols c0..c0+31)
    auto stage = [&](int r0, int c0) {
#pragma unroll
        for (int it = 0; it < 4; ++it) {
            int m = tid + it * 256;      // 0..1023
            int j = m & 31, i = m >> 5;  // col-in-panel, row-in-half
            const float* gp = Sg + ((((size_t)b * TN + r0 + i) * TN + c0 + j) * LN + lg * 4);
            float4 v = *(const float4*)gp;
            int off = i * 32 + chunk_pos(j >> 2, i) * 4 + (j & 3);
            st[0 * 1024 + off] = v.x;
            st[1 * 1024 + off] = v.y;
            st[2 * 1024 + off] = v.z;
            st[3 * 1024 + off] = v.w;
        }
    };

    float tr = 0.0f, sm = 0.0f, logdet = 0.0f;
    float r1[HN];

    // ---- panel 1 (cols 0..31) ----
    stage(0, 0);
    __syncthreads();
    if (lane < 32) fillp<0>(r1, plane, slot);
    __syncthreads();
    stage(32, 0);
    __syncthreads();
    if (lane >= 32) fillp<0>(r1, plane, slot);

    trace_half<0, 0>(r1, kp, mu, tr, sm);
    c1_sweep<0>(r1, logdet);             // r1 now holds multipliers c_0..31

    // ---- panel 2 (cols 32..63) ----
    __syncthreads();                     // all waves done reading panel-1 LDS
    float r2[HN];
    stage(0, 32);
    __syncthreads();
    if (lane < 32) fillp<0>(r2, plane, slot);
    __syncthreads();
    stage(32, 32);
    __syncthreads();
    if (lane >= 32) fillp<0>(r2, plane, slot);

    trace_half<32, 0>(r2, kp + 32, mu, tr, sm);
    rep_sweep<0>(r2, r1);                // deferred right-half updates
    solo_sweep<0>(r2, logdet);           // trailing 32x32 pivots

    float contrib = tr + mu * sm;
#pragma unroll
    for (int off = 32; off >= 1; off >>= 1) contrib += __shfl_xor(contrib, off, 64);

    if (lane == 0) {
        float klp = 0.5f * (logdetK[l] - logdet - (float)TN + contrib);
        atomicAdd(&out[b], klp);
    }
}

// ======================== fused k_ll + k_kinv (unchanged) ==================
template<int J>
__device__ __forceinline__ void pan_load(float (&p)[HN], const float* __restrict__ Kmat,
                                         int i, int l, int jbase) {
    if constexpr (J < HN) {
        p[J] = Kmat[(i * TN + jbase + J) * LN + l];
        pan_load<J + 1>(p, Kmat, i, l, jbase);
    }
}
template<int K, int J>
__device__ __forceinline__ void ki_upd(float (&a)[HN], float c) {
    if constexpr (J < HN) {
        a[J] = fmaf(-c, bcastf(a[J], K), a[J]);
        ki_upd<K, J + 1>(a, c);
    }
}
template<int K>
__device__ __forceinline__ void ki_a1sweep(float (&a1)[HN], float& ld, float& piv, int i) {
    if constexpr (K < HN) {
        float dkk = bcastf(a1[K], K);
        ld += __logf(dkk);
        if (i == K) piv = dkk;
        float c = (i == K) ? 0.0f : a1[K] * __builtin_amdgcn_rcpf(dkk);
        ki_upd<K, K + 1>(a1, c);
        a1[K] = c;                        // multiplier -> dead slot
        ki_a1sweep<K + 1>(a1, ld, piv, i);
    }
}
template<int K>
__device__ __forceinline__ void ki_replay(float (&a2)[HN], const float (&a1)[HN]) {
    if constexpr (K < HN) {
        ki_upd<K, 0>(a2, a1[K]);
        ki_replay<K + 1>(a2, a1);
    }
}
template<int Q, int J>
__device__ __forceinline__ void ki_upd2(float (&a2)[HN], float c) {
    if constexpr (J < HN) {
        a2[J] = fmaf(-c, bcastf(a2[J], 32 + Q), a2[J]);
        ki_upd2<Q, J + 1>(a2, c);
    }
}
template<int Q>
__device__ __forceinline__ void ki_a2sweep(float (&a2)[HN], float& ld, float& piv, int i) {
    if constexpr (Q < HN) {
        float dkk = bcastf(a2[Q], 32 + Q);
        ld += __logf(dkk);
        if (i == 32 + Q) piv = dkk;
        float c = (i == 32 + Q) ? 0.0f : a2[Q] * __builtin_amdgcn_rcpf(dkk);
        ki_upd2<Q, Q + 1>(a2, c);
        a2[Q] = c;                        // multiplier -> dead slot
        ki_a2sweep<Q + 1>(a2, ld, piv, i);
    }
}
template<int J>
__device__ __forceinline__ void g1_init(float (&g)[HN], int i) {
    if constexpr (J < HN) { g[J] = (J == i) ? 1.0f : 0.0f; g1_init<J + 1>(g, i); }
}
template<int K, int J>
__device__ __forceinline__ void g1_updA(float (&g)[HN], float c) {
    if constexpr (J <= K) {
        g[J] = fmaf(-c, bcastf(g[J], K), g[J]);
        g1_updA<K, J + 1>(g, c);
    }
}
template<int K>
__device__ __forceinline__ void g1_phase1(float (&g)[HN], const float (&a1)[HN]) {
    if constexpr (K < HN) {
        g1_updA<K, 0>(g, a1[K]);
        g1_phase1<K + 1>(g, a1);
    }
}
template<int Q, int J>
__device__ __forceinline__ void g1_updB(float (&g)[HN], float c) {
    if constexpr (J < HN) {
        g[J] = fmaf(-c, bcastf(g[J], 32 + Q), g[J]);
        g1_updB<Q, J + 1>(g, c);
    }
}
template<int Q>
__device__ __forceinline__ void g1_phase2(float (&g)[HN], const float (&a2)[HN]) {
    if constexpr (Q < HN) {
        g1_updB<Q, 0>(g, a2[Q]);
        g1_phase2<Q + 1>(g, a2);
    }
}
template<int J>
__device__ __forceinline__ void g2_init(float (&g)[HN], int i) {
    if constexpr (J < HN) { g[J] = (32 + J == i) ? 1.0f : 0.0f; g2_init<J + 1>(g, i); }
}
template<int Q, int J>
__device__ __forceinline__ void g2_upd(float (&g)[HN], float c) {
    if constexpr (J <= Q) {
        g[J] = fmaf(-c, bcastf(g[J], 32 + Q), g[J]);
        g2_upd<Q, J + 1>(g, c);
    }
}
template<int Q>
__device__ __forceinline__ void g2_phase(float (&g)[HN], const float (&a2)[HN]) {
    if constexpr (Q < HN) {
        g2_upd<Q, 0>(g, a2[Q]);
        g2_phase<Q + 1>(g, a2);
    }
}
template<int J>
__device__ __forceinline__ void pan_out(const float (&g)[HN], float rdi,
                                        float* __restrict__ dst) {
    if constexpr (J < HN) {
        dst[J] = g[J] * rdi;
        pan_out<J + 1>(g, rdi, dst);
    }
}

__global__ __launch_bounds__(256)
void k_ll_kinv(const float* __restrict__ X,
               const float* __restrict__ Mn,
               const float* __restrict__ R,
               const float* __restrict__ Kmat,
               float* __restrict__ kinv,
               float* __restrict__ logdetK,
               float* __restrict__ out) {
    if (blockIdx.x < 32) {
        if (threadIdx.x >= 64) return;
        const int l = blockIdx.x;
        const int i = threadIdx.x;       // row

        float ld = 0.0f, piv = 1.0f;
        float a1[HN], a2[HN];
        pan_load<0>(a1, Kmat, i, l, 0);
        ki_a1sweep<0>(a1, ld, piv, i);
        pan_load<0>(a2, Kmat, i, l, 32);
        ki_replay<0>(a2, a1);
        ki_a2sweep<0>(a2, ld, piv, i);
        float rdi = __builtin_amdgcn_rcpf(piv);
        {
            float g2[HN];
            g2_init<0>(g2, i);
            g2_phase<0>(g2, a2);
            pan_out<0>(g2, rdi, kinv + l * (TN * TN) + i * TN + 32);
        }
        {
            float g1[HN];
            g1_init<0>(g1, i);
            g1_phase1<0>(g1, a1);
            g1_phase2<0>(g1, a2);
            pan_out<0>(g1, rdi, kinv + l * (TN * TN) + i * TN);
        }
        if (i == 0) logdetK[l] = ld;
        return;
    }

    // ---- log-likelihood block (b,s) ----
    int hw = blockIdx.x - 32;            // 1024 blocks
    int g = (hw & 7) * 128 + (hw >> 3);
    int b = g >> 2, s = g & 3;
    int tid = threadIdx.x;

    const float4* xp = (const float4*)(X + (size_t)b * TN * DN);
    const float4* mp = (const float4*)(Mn + ((size_t)(b * SN + s) * TN) * DN);

    int c = tid & 31;
    float4 rv = ((const float4*)R)[c];
    float4 ri = make_float4(1.0f / rv.x, 1.0f / rv.y, 1.0f / rv.z, 1.0f / rv.w);

    float acc = 0.0f;
#pragma unroll
    for (int it = 0; it < (TN * DN / 4) / 256; ++it) {
        int f = tid + it * 256;
        float4 xv = xp[f];
        float4 mv = mp[f];
        float dx = xv.x - mv.x; acc = fmaf(dx * dx, ri.x, acc);
        float dy = xv.y - mv.y; acc = fmaf(dy * dy, ri.y, acc);
        float dz = xv.z - mv.z; acc = fmaf(dz * dz, ri.z, acc);
        float dw = xv.w - mv.w; acc = fmaf(dw * dw, ri.w, acc);
    }
#pragma unroll
    for (int off = 32; off >= 1; off >>= 1) acc += __shfl_xor(acc, off, 64);

    __shared__ float wsum[4];
    if ((tid & 63) == 0) wsum[tid >> 6] = acc;
    __syncthreads();
    if (tid == 0) {
        float q = wsum[0] + wsum[1] + wsum[2] + wsum[3];
        float val = q * (0.5f / SN);
        if (s == 0) {
            float slr = 0.0f;
#pragma unroll
            for (int d = 0; d < DN; ++d) slr += __logf(R[d]);
            val += 0.5f * (float)TN * (slr + (float)DN * LOG2PI);
        }
        atomicAdd(&out[b], val);
    }
}

// ---------------------------------------------------------------------------
extern "C" void kernel_launch(void* const* d_in, const int* in_sizes, int n_in,
                              void* d_out, int out_size, void* d_ws, size_t ws_size,
                              hipStream_t stream) {
    const float* X   = (const float*)d_in[0];  // [B,T,D]
    const float* Mn  = (const float*)d_in[1];  // [B,S,T,D]
    const float* R   = (const float*)d_in[2];  // [D]
    const float* mus = (const float*)d_in[3];  // [B,T,L]
    const float* Sg  = (const float*)d_in[4];  // [B,T,T,L]
    const float* Km  = (const float*)d_in[5];  // [T,T,L]
    float* out = (float*)d_out;                // [B] fp32

    float* kinv = (float*)d_ws;                // 32*4096 floats = 512 KB
    float* ldK  = kinv + LN * TN * TN;         // 32 floats

    hipMemsetAsync(d_out, 0, BN * sizeof(float), stream);
    k_ll_kinv<<<32 + BN * SN, 256, 0, stream>>>(X, Mn, R, Km, kinv, ldK, out);
    k_chol<<<BN * 8, 256, 0, stream>>>(Sg, mus, kinv, ldK, out);
}

// Round 10
// 152.915 us; speedup vs baseline: 1.3543x; 1.3543x over previous
//
#include <hip/hip_runtime.h>
#include <math.h>

// Problem constants
#define BN 256
#define TN 64
#define LN 32
#define DN 128
#define SN 4
#define HN 32   // column-panel width for the blocked elimination

#define LOG2PI 1.8378770664093453f

typedef __attribute__((ext_vector_type(2))) float f32x2;

__device__ __forceinline__ float bcastf(float v, int lane) {
    return __builtin_bit_cast(float, __builtin_amdgcn_readlane(__builtin_bit_cast(int, v), lane));
}
// two readlanes -> one SGPR pair (compiler folds to REG_SEQUENCE; SALU is free)
__device__ __forceinline__ unsigned long long rl2(float va, float vb, int la, int lb) {
    unsigned lo = (unsigned)__builtin_amdgcn_readlane(__builtin_bit_cast(int, va), la);
    unsigned hi = (unsigned)__builtin_amdgcn_readlane(__builtin_bit_cast(int, vb), lb);
    return ((unsigned long long)hi << 32) | lo;
}
// acc += a * s  (packed dual fp32 FMA; s = wave-uniform SGPR pair)
__device__ __forceinline__ void pkfma_s(f32x2& acc, f32x2 a, unsigned long long s) {
    asm("v_pk_fma_f32 %0, %1, %2, %0" : "+v"(acc) : "v"(a), "s"(s));
}
__device__ __forceinline__ void pkfma_v(f32x2& acc, f32x2 a, f32x2 b) {
    asm("v_pk_fma_f32 %0, %1, %2, %0" : "+v"(acc) : "v"(a), "v"(b));
}
// bf16-truncation pack of multipliers: 2 per VGPR, shift-only
__device__ __forceinline__ float bf_lo(unsigned m) { return __builtin_bit_cast(float, m << 16); }
__device__ __forceinline__ float bf_hi(unsigned m) { return __builtin_bit_cast(float, m & 0xFFFF0000u); }

// ===========================================================================
// Lessons R1-R9:
//  * Per-lane array subscripts must be frontend-time constants (templates).
//  * >64 live floats -> AGPR parking (R5); forced min-occupancy
//    (launch_bounds arg2 / waves_per_eu min) -> RA cannot relax -> scratch
//    storm (R9: VGPR 32, 160MB writes). Never set occupancy floors.
//  * This round: peak live <= ~60 via bf16-packed multipliers (16 VGPRs
//    instead of 32) + pk_fma pairs -> fits default 64-budget -> 8 blocks/CU
//    with 16KB LDS, no attributes.
// ===========================================================================

// LDS plane layout: [32 rows][8 chunks][4 dwords]; chunk q of row i at
// position (q + i + (i>>3)) & 7 (proven R8/R9).
__device__ __forceinline__ int chunk_pos(int q, int i) { return (q + i + (i >> 3)) & 7; }

template<int Q>
__device__ __forceinline__ void fillp2(f32x2 (&r)[16], const float* plane, int slot) {
    if constexpr (Q < 8) {
        const float4 v = *(const float4*)(plane + slot * 32 + chunk_pos(Q, slot) * 4);
        r[2 * Q].x = v.x; r[2 * Q].y = v.y;
        r[2 * Q + 1].x = v.z; r[2 * Q + 1].y = v.w;
        fillp2<Q + 1>(r, plane, slot);
    }
}
// trace: tr2 += kv*r (vector); sm2 += kv*{mu_j,mu_j+1} (uniform gather)
template<int JBASE, int J2>
__device__ __forceinline__ void trace_pk(const f32x2 (&r)[16], const float* __restrict__ kp,
                                         float mu, f32x2& tr2, f32x2& sm2) {
    if constexpr (J2 < 16) {
        f32x2 kv = *(const f32x2*)(kp + 2 * J2);
        pkfma_v(tr2, kv, r[J2]);
        pkfma_s(sm2, kv, rl2(mu, mu, JBASE + 2 * J2, JBASE + 2 * J2 + 1));
        trace_pk<JBASE, J2 + 1>(r, kp, mu, tr2, sm2);
    }
}

// ---- pivots 0..31 on cols 0..31 (symmetric gather: A[K][J] = lane J's rk) --
template<int K, int J2>
__device__ __forceinline__ void c1_updp(f32x2 (&r)[16], f32x2 cn2, float rk) {
    if constexpr (J2 < 16) {
        pkfma_s(r[J2], cn2, rl2(rk, rk, 2 * J2, 2 * J2 + 1));
        c1_updp<K, J2 + 1>(r, cn2, rk);
    }
}
template<int K>
__device__ __forceinline__ void c1_sweep(f32x2 (&r)[16], unsigned (&m)[16], float& logdet) {
    if constexpr (K < 32) {
        float rk = (K & 1) ? r[K >> 1].y : r[K >> 1].x;   // own col-K (copy)
        float d = bcastf(rk, K);
        logdet += __logf(d);
        float c = rk * __builtin_amdgcn_rcpf(d);
        f32x2 cn2; cn2.x = -c; cn2.y = -c;
        // pairs from (K+1)/2: col K may be garbage-written (dead), col<K never touched
        c1_updp<K, (K + 1) / 2>(r, cn2, rk);
        if constexpr (K & 1) m[K >> 1] |= (__builtin_bit_cast(unsigned, c) & 0xFFFF0000u);
        else                 m[K >> 1]  = (__builtin_bit_cast(unsigned, c) >> 16);
        c1_sweep<K + 1>(r, m, logdet);
    }
}
// ---- replay pivots 0..31 onto cols 32..63 (row K lives in lane K's r2) ----
template<int K, int J2>
__device__ __forceinline__ void rep_updp(f32x2 (&r2)[16], f32x2 cn2) {
    if constexpr (J2 < 16) {
        pkfma_s(r2[J2], cn2, rl2(r2[J2].x, r2[J2].y, K, K));
        rep_updp<K, J2 + 1>(r2, cn2);
    }
}
template<int K>
__device__ __forceinline__ void rep_sweep(f32x2 (&r2)[16], const unsigned (&m)[16]) {
    if constexpr (K < 32) {
        float c = (K & 1) ? bf_hi(m[K >> 1]) : bf_lo(m[K >> 1]);
        f32x2 cn2; cn2.x = -c; cn2.y = -c;
        rep_updp<K, 0>(r2, cn2);
        rep_sweep<K + 1>(r2, m);
    }
}
// ---- pivots 32..63 on trailing 32x32 (symmetric gather from lanes 32+J) ---
template<int Q, int J2>
__device__ __forceinline__ void solo_updp(f32x2 (&r2)[16], f32x2 cn2, float rq) {
    if constexpr (J2 < 16) {
        pkfma_s(r2[J2], cn2, rl2(rq, rq, 32 + 2 * J2, 32 + 2 * J2 + 1));
        solo_updp<Q, J2 + 1>(r2, cn2, rq);
    }
}
template<int Q>
__device__ __forceinline__ void solo_sweep(f32x2 (&r2)[16], float& logdet) {
    if constexpr (Q < 32) {
        float rq = (Q & 1) ? r2[Q >> 1].y : r2[Q >> 1].x;
        float d = bcastf(rq, 32 + Q);
        logdet += __logf(d);
        float c = rq * __builtin_amdgcn_rcpf(d);
        f32x2 cn2; cn2.x = -c; cn2.y = -c;
        solo_updp<Q, (Q + 1) / 2>(r2, cn2, rq);
        solo_sweep<Q + 1>(r2, logdet);
    }
}

// ---------------------------------------------------------------------------
// k_chol: block = 256 threads = 4 waves = one (b, l-quad); 16KB LDS staging
// (32-row half-panels, R9's proven indexing); peak live <=~60 floats.
// ---------------------------------------------------------------------------
__global__ __launch_bounds__(256)
void k_chol(const float* __restrict__ Sg,
            const float* __restrict__ mus,
            const float* __restrict__ kinv,
            const float* __restrict__ logdetK,
            float* __restrict__ out) {
    __shared__ float st[4 * 1024];       // 16 KB

    int hw = blockIdx.x;                 // 2048 blocks = 8/CU, one round
    int g = (hw & 7) * 256 + (hw >> 3);  // XCD x owns b in [x*32, x*32+32)
    int b = g >> 3, lg = g & 7;

    int tid = threadIdx.x;
    int w = tid >> 6, lane = tid & 63;   // wave w <-> l = lg*4 + w; lane = row
    int l = lg * 4 + w;
    int slot = lane & 31;

    float mu = mus[((size_t)b * TN + lane) * LN + l];
    const float* kp = kinv + l * (TN * TN) + lane * TN;
    const float* plane = &st[w * 1024];

    auto stage = [&](int r0, int c0) {
#pragma unroll
        for (int it = 0; it < 4; ++it) {
            int m_ = tid + it * 256;     // 0..1023
            int j = m_ & 31, i = m_ >> 5;
            const float* gp = Sg + ((((size_t)b * TN + r0 + i) * TN + c0 + j) * LN + lg * 4);
            float4 v = *(const float4*)gp;
            int off = i * 32 + chunk_pos(j >> 2, i) * 4 + (j & 3);
            st[0 * 1024 + off] = v.x;
            st[1 * 1024 + off] = v.y;
            st[2 * 1024 + off] = v.z;
            st[3 * 1024 + off] = v.w;
        }
    };

    f32x2 tr2 = {0.0f, 0.0f}, sm2 = {0.0f, 0.0f};
    float logdet = 0.0f;
    unsigned m[16];
    f32x2 r1[16];

    // ---- panel 1 (cols 0..31) ----
    stage(0, 0);
    __syncthreads();
    if (lane < 32) fillp2<0>(r1, plane, slot);
    __syncthreads();
    stage(32, 0);
    __syncthreads();
    if (lane >= 32) fillp2<0>(r1, plane, slot);

    trace_pk<0, 0>(r1, kp, mu, tr2, sm2);
    c1_sweep<0>(r1, m, logdet);          // mults -> bf16-packed m[16]; r1 dead

    // ---- panel 2 (cols 32..63) ----
    __syncthreads();                     // all waves done with panel-1 LDS
    f32x2 r2[16];
    stage(0, 32);
    __syncthreads();
    if (lane < 32) fillp2<0>(r2, plane, slot);
    __syncthreads();
    stage(32, 32);
    __syncthreads();
    if (lane >= 32) fillp2<0>(r2, plane, slot);

    trace_pk<32, 0>(r2, kp + 32, mu, tr2, sm2);
    float trs = tr2.x + tr2.y, sms = sm2.x + sm2.y;   // shrink live set
    rep_sweep<0>(r2, m);                 // deferred right-half updates
    solo_sweep<0>(r2, logdet);           // trailing 32x32 pivots

    float contrib = trs + mu * sms;
#pragma unroll
    for (int off = 32; off >= 1; off >>= 1) contrib += __shfl_xor(contrib, off, 64);

    if (lane == 0) {
        float klp = 0.5f * (logdetK[l] - logdet - (float)TN + contrib);
        atomicAdd(&out[b], klp);
    }
}

// ======================== fused k_ll + k_kinv ==============================
// kinv: R8's proven scalar templates; NOW 2 blocks per latent (redundant
// sweeps, split g1/g2 reconstruction) to halve the serial critical path.
template<int J>
__device__ __forceinline__ void pan_load(float (&p)[HN], const float* __restrict__ Kmat,
                                         int i, int l, int jbase) {
    if constexpr (J < HN) {
        p[J] = Kmat[(i * TN + jbase + J) * LN + l];
        pan_load<J + 1>(p, Kmat, i, l, jbase);
    }
}
template<int K, int J>
__device__ __forceinline__ void ki_upd(float (&a)[HN], float c) {
    if constexpr (J < HN) {
        a[J] = fmaf(-c, bcastf(a[J], K), a[J]);
        ki_upd<K, J + 1>(a, c);
    }
}
template<int K>
__device__ __forceinline__ void ki_a1sweep(float (&a1)[HN], float& ld, float& piv, int i) {
    if constexpr (K < HN) {
        float dkk = bcastf(a1[K], K);
        ld += __logf(dkk);
        if (i == K) piv = dkk;
        float c = (i == K) ? 0.0f : a1[K] * __builtin_amdgcn_rcpf(dkk);
        ki_upd<K, K + 1>(a1, c);
        a1[K] = c;
        ki_a1sweep<K + 1>(a1, ld, piv, i);
    }
}
template<int K>
__device__ __forceinline__ void ki_replay(float (&a2)[HN], const float (&a1)[HN]) {
    if constexpr (K < HN) {
        ki_upd<K, 0>(a2, a1[K]);
        ki_replay<K + 1>(a2, a1);
    }
}
template<int Q, int J>
__device__ __forceinline__ void ki_upd2(float (&a2)[HN], float c) {
    if constexpr (J < HN) {
        a2[J] = fmaf(-c, bcastf(a2[J], 32 + Q), a2[J]);
        ki_upd2<Q, J + 1>(a2, c);
    }
}
template<int Q>
__device__ __forceinline__ void ki_a2sweep(float (&a2)[HN], float& ld, float& piv, int i) {
    if constexpr (Q < HN) {
        float dkk = bcastf(a2[Q], 32 + Q);
        ld += __logf(dkk);
        if (i == 32 + Q) piv = dkk;
        float c = (i == 32 + Q) ? 0.0f : a2[Q] * __builtin_amdgcn_rcpf(dkk);
        ki_upd2<Q, Q + 1>(a2, c);
        a2[Q] = c;
        ki_a2sweep<Q + 1>(a2, ld, piv, i);
    }
}
template<int J>
__device__ __forceinline__ void g1_init(float (&g)[HN], int i) {
    if constexpr (J < HN) { g[J] = (J == i) ? 1.0f : 0.0f; g1_init<J + 1>(g, i); }
}
template<int K, int J>
__device__ __forceinline__ void g1_updA(float (&g)[HN], float c) {
    if constexpr (J <= K) {
        g[J] = fmaf(-c, bcastf(g[J], K), g[J]);
        g1_updA<K, J + 1>(g, c);
    }
}
template<int K>
__device__ __forceinline__ void g1_phase1(float (&g)[HN], const float (&a1)[HN]) {
    if constexpr (K < HN) {
        g1_updA<K, 0>(g, a1[K]);
        g1_phase1<K + 1>(g, a1);
    }
}
template<int Q, int J>
__device__ __forceinline__ void g1_updB(float (&g)[HN], float c) {
    if constexpr (J < HN) {
        g[J] = fmaf(-c, bcastf(g[J], 32 + Q), g[J]);
        g1_updB<Q, J + 1>(g, c);
    }
}
template<int Q>
__device__ __forceinline__ void g1_phase2(float (&g)[HN], const float (&a2)[HN]) {
    if constexpr (Q < HN) {
        g1_updB<Q, 0>(g, a2[Q]);
        g1_phase2<Q + 1>(g, a2);
    }
}
template<int J>
__device__ __forceinline__ void g2_init(float (&g)[HN], int i) {
    if constexpr (J < HN) { g[J] = (32 + J == i) ? 1.0f : 0.0f; g2_init<J + 1>(g, i); }
}
template<int Q, int J>
__device__ __forceinline__ void g2_upd(float (&g)[HN], float c) {
    if constexpr (J <= Q) {
        g[J] = fmaf(-c, bcastf(g[J], 32 + Q), g[J]);
        g2_upd<Q, J + 1>(g, c);
    }
}
template<int Q>
__device__ __forceinline__ void g2_phase(float (&g)[HN], const float (&a2)[HN]) {
    if constexpr (Q < HN) {
        g2_upd<Q, 0>(g, a2[Q]);
        g2_phase<Q + 1>(g, a2);
    }
}
template<int J>
__device__ __forceinline__ void pan_out(const float (&g)[HN], float rdi,
                                        float* __restrict__ dst) {
    if constexpr (J < HN) {
        dst[J] = g[J] * rdi;
        pan_out<J + 1>(g, rdi, dst);
    }
}

__global__ __launch_bounds__(256)
void k_ll_kinv(const float* __restrict__ X,
               const float* __restrict__ Mn,
               const float* __restrict__ R,
               const float* __restrict__ Kmat,
               float* __restrict__ kinv,
               float* __restrict__ logdetK,
               float* __restrict__ out) {
    if (blockIdx.x < 64) {
        // 2 blocks per latent: both redo the sweeps, split the reconstruction
        if (threadIdx.x >= 64) return;
        const int l = blockIdx.x >> 1;
        const int half = blockIdx.x & 1;
        const int i = threadIdx.x;       // row

        float ld = 0.0f, piv = 1.0f;
        float a1[HN], a2[HN];
        pan_load<0>(a1, Kmat, i, l, 0);
        ki_a1sweep<0>(a1, ld, piv, i);
        pan_load<0>(a2, Kmat, i, l, 32);
        ki_replay<0>(a2, a1);
        ki_a2sweep<0>(a2, ld, piv, i);
        float rdi = __builtin_amdgcn_rcpf(piv);
        if (half == 0) {
            float g1[HN];
            g1_init<0>(g1, i);
            g1_phase1<0>(g1, a1);
            g1_phase2<0>(g1, a2);
            pan_out<0>(g1, rdi, kinv + l * (TN * TN) + i * TN);
        } else {
            float g2[HN];
            g2_init<0>(g2, i);
            g2_phase<0>(g2, a2);
            pan_out<0>(g2, rdi, kinv + l * (TN * TN) + i * TN + 32);
            if (i == 0) logdetK[l] = ld;
        }
        return;
    }

    // ---- log-likelihood block (b,s) ----
    int hw = blockIdx.x - 64;            // 1024 blocks
    int g = (hw & 7) * 128 + (hw >> 3);
    int b = g >> 2, s = g & 3;
    int tid = threadIdx.x;

    const float4* xp = (const float4*)(X + (size_t)b * TN * DN);
    const float4* mp = (const float4*)(Mn + ((size_t)(b * SN + s) * TN) * DN);

    int c = tid & 31;
    float4 rv = ((const float4*)R)[c];
    float4 ri = make_float4(1.0f / rv.x, 1.0f / rv.y, 1.0f / rv.z, 1.0f / rv.w);

    float acc = 0.0f;
#pragma unroll
    for (int it = 0; it < (TN * DN / 4) / 256; ++it) {
        int f = tid + it * 256;
        float4 xv = xp[f];
        float4 mv = mp[f];
        float dx = xv.x - mv.x; acc = fmaf(dx * dx, ri.x, acc);
        float dy = xv.y - mv.y; acc = fmaf(dy * dy, ri.y, acc);
        float dz = xv.z - mv.z; acc = fmaf(dz * dz, ri.z, acc);
        float dw = xv.w - mv.w; acc = fmaf(dw * dw, ri.w, acc);
    }
#pragma unroll
    for (int off = 32; off >= 1; off >>= 1) acc += __shfl_xor(acc, off, 64);

    __shared__ float wsum[4];
    if ((tid & 63) == 0) wsum[tid >> 6] = acc;
    __syncthreads();
    if (tid == 0) {
        float q = wsum[0] + wsum[1] + wsum[2] + wsum[3];
        float val = q * (0.5f / SN);
        if (s == 0) {
            float slr = 0.0f;
#pragma unroll
            for (int d = 0; d < DN; ++d) slr += __logf(R[d]);
            val += 0.5f * (float)TN * (slr + (float)DN * LOG2PI);
        }
        atomicAdd(&out[b], val);
    }
}

// ---------------------------------------------------------------------------
extern "C" void kernel_launch(void* const* d_in, const int* in_sizes, int n_in,
                              void* d_out, int out_size, void* d_ws, size_t ws_size,
                              hipStream_t stream) {
    const float* X   = (const float*)d_in[0];  // [B,T,D]
    const float* Mn  = (const float*)d_in[1];  // [B,S,T,D]
    const float* R   = (const float*)d_in[2];  // [D]
    const float* mus = (const float*)d_in[3];  // [B,T,L]
    const float* Sg  = (const float*)d_in[4];  // [B,T,T,L]
    const float* Km  = (const float*)d_in[5];  // [T,T,L]
    float* out = (float*)d_out;                // [B] fp32

    float* kinv = (float*)d_ws;                // 32*4096 floats = 512 KB
    float* ldK  = kinv + LN * TN * TN;         // 32 floats

    hipMemsetAsync(d_out, 0, BN * sizeof(float), stream);
    k_ll_kinv<<<64 + BN * SN, 256, 0, stream>>>(X, Mn, R, Km, kinv, ldK, out);
    k_chol<<<BN * 8, 256, 0, stream>>>(Sg, mus, kinv, ldK, out);
}

// Round 11
// 146.756 us; speedup vs baseline: 1.4112x; 1.0420x over previous
//
#include <hip/hip_runtime.h>
#include <math.h>

// Problem constants
#define BN 256
#define TN 64
#define LN 32
#define DN 128
#define SN 4
#define HN 32   // column-panel width for the blocked elimination

#define LOG2PI 1.8378770664093453f

__device__ __forceinline__ float bcastf(float v, int lane) {
    return __builtin_bit_cast(float, __builtin_amdgcn_readlane(__builtin_bit_cast(int, v), lane));
}
// bf16-truncation pack of multipliers: 2 per VGPR, shift-only (R10-verified safe)
__device__ __forceinline__ float bf_lo(unsigned m) { return __builtin_bit_cast(float, m << 16); }
__device__ __forceinline__ float bf_hi(unsigned m) { return __builtin_bit_cast(float, m & 0xFFFF0000u); }

// ===========================================================================
// Lessons R1-R10:
//  * Per-lane array subscripts must be frontend-time constants (templates).
//  * >64 live floats -> AGPR parking (R5). Min-occupancy mandates -> RA
//    cannot relax -> scratch storm (R9). Inline-asm pk_fma / f32x2 pairs ->
//    +36 VGPR of alignment pressure (R10). Plain scalar fmaf + readlane is
//    the fastest verified form (R8: 52 VGPR, zero scratch).
//  * This round = the three PROVEN pieces combined, nothing else:
//    R8 scalar sweeps + R9 16KB half-panel staging + R10 bf16-packed
//    multipliers (peak live ~58 floats) -> default allocator -> 8 blocks/CU.
// ===========================================================================

// LDS plane layout: [32 rows][8 chunks][4 dwords]; chunk q of row i at
// position (q + i + (i>>3)) & 7 -> conflict-free b128 fills & staging stores.
__device__ __forceinline__ int chunk_pos(int q, int i) { return (q + i + (i >> 3)) & 7; }

// ---- shared template helpers ---------------------------------------------
template<int Q>
__device__ __forceinline__ void fillp(float (&r)[HN], const float* plane, int slot) {
    if constexpr (Q < 8) {
        const float4 v = *(const float4*)(plane + slot * 32 + chunk_pos(Q, slot) * 4);
        r[4 * Q + 0] = v.x; r[4 * Q + 1] = v.y;
        r[4 * Q + 2] = v.z; r[4 * Q + 3] = v.w;
        fillp<Q + 1>(r, plane, slot);
    }
}
template<int JBASE, int J4>
__device__ __forceinline__ void trace_half(const float (&r)[HN], const float* __restrict__ kp,
                                           float mu, float& tr, float& sm) {
    if constexpr (J4 < 8) {
        float4 kv = *(const float4*)(kp + 4 * J4);
        tr = fmaf(kv.x, r[4 * J4 + 0], tr); sm = fmaf(kv.x, bcastf(mu, JBASE + 4 * J4 + 0), sm);
        tr = fmaf(kv.y, r[4 * J4 + 1], tr); sm = fmaf(kv.y, bcastf(mu, JBASE + 4 * J4 + 1), sm);
        tr = fmaf(kv.z, r[4 * J4 + 2], tr); sm = fmaf(kv.z, bcastf(mu, JBASE + 4 * J4 + 2), sm);
        tr = fmaf(kv.w, r[4 * J4 + 3], tr); sm = fmaf(kv.w, bcastf(mu, JBASE + 4 * J4 + 3), sm);
        trace_half<JBASE, J4 + 1>(r, kp, mu, tr, sm);
    }
}

// ---- k_chol sweeps: scalar fmaf + readlane; mults bf16-packed ------------
// pivots 0..31 on cols 0..31; symmetric trailing read: A[K][J] = lane J's r1[K].
template<int K, int J>
__device__ __forceinline__ void c1_upd(float (&r1)[HN], float c) {
    if constexpr (J < HN) {
        r1[J] = fmaf(-c, bcastf(r1[K], J), r1[J]);
        c1_upd<K, J + 1>(r1, c);
    }
}
template<int K>
__device__ __forceinline__ void c1_sweep(float (&r1)[HN], unsigned (&m)[16], float& logdet) {
    if constexpr (K < HN) {
        float dkk = bcastf(r1[K], K);
        logdet += __logf(dkk);
        float c = r1[K] * __builtin_amdgcn_rcpf(dkk);
        c1_upd<K, K + 1>(r1, c);
        // pack multiplier (bf16 truncate); r1[K] is dead hereafter
        if constexpr (K & 1) m[K >> 1] |= (__builtin_bit_cast(unsigned, c) & 0xFFFF0000u);
        else                 m[K >> 1]  = (__builtin_bit_cast(unsigned, c) >> 16);
        c1_sweep<K + 1>(r1, m, logdet);
    }
}
// replay pivots 0..31 onto cols 32..63; pivot row K's right half = lane K's
// r2 (exact through step K; its self-update happens after the bcast read).
template<int K, int J>
__device__ __forceinline__ void rep_upd(float (&r2)[HN], float c) {
    if constexpr (J < HN) {
        r2[J] = fmaf(-c, bcastf(r2[J], K), r2[J]);
        rep_upd<K, J + 1>(r2, c);
    }
}
template<int K>
__device__ __forceinline__ void rep_sweep(float (&r2)[HN], const unsigned (&m)[16]) {
    if constexpr (K < HN) {
        float c = (K & 1) ? bf_hi(m[K >> 1]) : bf_lo(m[K >> 1]);
        rep_upd<K, 0>(r2, c);
        rep_sweep<K + 1>(r2, m);
    }
}
// pivots 32..63 on trailing 32x32 (lanes 32..63 hold the Schur rows)
template<int Q, int J>
__device__ __forceinline__ void solo_upd(float (&r2)[HN], float c) {
    if constexpr (J < HN) {
        r2[J] = fmaf(-c, bcastf(r2[Q], 32 + J), r2[J]);
        solo_upd<Q, J + 1>(r2, c);
    }
}
template<int Q>
__device__ __forceinline__ void solo_sweep(float (&r2)[HN], float& logdet) {
    if constexpr (Q < HN) {
        float dkk = bcastf(r2[Q], 32 + Q);
        logdet += __logf(dkk);
        float c = r2[Q] * __builtin_amdgcn_rcpf(dkk);
        solo_upd<Q, Q + 1>(r2, c);
        solo_sweep<Q + 1>(r2, logdet);
    }
}

// ---------------------------------------------------------------------------
// k_chol: block = 256 threads = 4 waves = one (b, l-quad).
// LDS = 4 planes x 32x32 half-panel = 16 KB; peak live ~58 floats ->
// default allocator <=64 VGPR -> 8 blocks/CU (32-wave cap), grid = one round.
// ---------------------------------------------------------------------------
__global__ __launch_bounds__(256)
void k_chol(const float* __restrict__ Sg,
            const float* __restrict__ mus,
            const float* __restrict__ kinv,
            const float* __restrict__ logdetK,
            float* __restrict__ out) {
    __shared__ float st[4 * 1024];       // 16 KB

    int hw = blockIdx.x;                 // 2048 blocks = 8/CU, one round
    int g = (hw & 7) * 256 + (hw >> 3);  // XCD x owns b in [x*32, x*32+32)
    int b = g >> 3, lg = g & 7;          // lg = l-quad 0..7

    int tid = threadIdx.x;
    int w = tid >> 6, lane = tid & 63;   // wave w <-> l = lg*4 + w; lane = row
    int l = lg * 4 + w;
    int slot = lane & 31;                // row within the staged half

    float mu = mus[((size_t)b * TN + lane) * LN + l];
    const float* kp = kinv + l * (TN * TN) + lane * TN;
    const float* plane = &st[w * 1024];

    // stage a 32-row x 32-col half-panel (rows r0..r0+31, cols c0..c0+31)
    auto stage = [&](int r0, int c0) {
#pragma unroll
        for (int it = 0; it < 4; ++it) {
            int m_ = tid + it * 256;     // 0..1023
            int j = m_ & 31, i = m_ >> 5;
            const float* gp = Sg + ((((size_t)b * TN + r0 + i) * TN + c0 + j) * LN + lg * 4);
            float4 v = *(const float4*)gp;
            int off = i * 32 + chunk_pos(j >> 2, i) * 4 + (j & 3);
            st[0 * 1024 + off] = v.x;
            st[1 * 1024 + off] = v.y;
            st[2 * 1024 + off] = v.z;
            st[3 * 1024 + off] = v.w;
        }
    };

    float tr = 0.0f, sm = 0.0f, logdet = 0.0f;
    unsigned m[16];
    float r1[HN];

    // ---- panel 1 (cols 0..31) ----
    stage(0, 0);
    __syncthreads();
    if (lane < 32) fillp<0>(r1, plane, slot);
    __syncthreads();
    stage(32, 0);
    __syncthreads();
    if (lane >= 32) fillp<0>(r1, plane, slot);

    trace_half<0, 0>(r1, kp, mu, tr, sm);
    c1_sweep<0>(r1, m, logdet);          // mults -> bf16-packed m[16]; r1 dead

    // ---- panel 2 (cols 32..63) ----
    __syncthreads();                     // all waves done with panel-1 LDS
    float r2[HN];
    stage(0, 32);
    __syncthreads();
    if (lane < 32) fillp<0>(r2, plane, slot);
    __syncthreads();
    stage(32, 32);
    __syncthreads();
    if (lane >= 32) fillp<0>(r2, plane, slot);

    trace_half<32, 0>(r2, kp + 32, mu, tr, sm);
    rep_sweep<0>(r2, m);                 // deferred right-half updates
    solo_sweep<0>(r2, logdet);           // trailing 32x32 pivots

    float contrib = tr + mu * sm;
#pragma unroll
    for (int off = 32; off >= 1; off >>= 1) contrib += __shfl_xor(contrib, off, 64);

    if (lane == 0) {
        float klp = 0.5f * (logdetK[l] - logdet - (float)TN + contrib);
        atomicAdd(&out[b], klp);
    }
}

// ======================== fused k_ll + k_kinv (R10, unchanged) =============
template<int J>
__device__ __forceinline__ void pan_load(float (&p)[HN], const float* __restrict__ Kmat,
                                         int i, int l, int jbase) {
    if constexpr (J < HN) {
        p[J] = Kmat[(i * TN + jbase + J) * LN + l];
        pan_load<J + 1>(p, Kmat, i, l, jbase);
    }
}
template<int K, int J>
__device__ __forceinline__ void ki_upd(float (&a)[HN], float c) {
    if constexpr (J < HN) {
        a[J] = fmaf(-c, bcastf(a[J], K), a[J]);
        ki_upd<K, J + 1>(a, c);
    }
}
template<int K>
__device__ __forceinline__ void ki_a1sweep(float (&a1)[HN], float& ld, float& piv, int i) {
    if constexpr (K < HN) {
        float dkk = bcastf(a1[K], K);
        ld += __logf(dkk);
        if (i == K) piv = dkk;
        float c = (i == K) ? 0.0f : a1[K] * __builtin_amdgcn_rcpf(dkk);
        ki_upd<K, K + 1>(a1, c);
        a1[K] = c;
        ki_a1sweep<K + 1>(a1, ld, piv, i);
    }
}
template<int K>
__device__ __forceinline__ void ki_replay(float (&a2)[HN], const float (&a1)[HN]) {
    if constexpr (K < HN) {
        ki_upd<K, 0>(a2, a1[K]);
        ki_replay<K + 1>(a2, a1);
    }
}
template<int Q, int J>
__device__ __forceinline__ void ki_upd2(float (&a2)[HN], float c) {
    if constexpr (J < HN) {
        a2[J] = fmaf(-c, bcastf(a2[J], 32 + Q), a2[J]);
        ki_upd2<Q, J + 1>(a2, c);
    }
}
template<int Q>
__device__ __forceinline__ void ki_a2sweep(float (&a2)[HN], float& ld, float& piv, int i) {
    if constexpr (Q < HN) {
        float dkk = bcastf(a2[Q], 32 + Q);
        ld += __logf(dkk);
        if (i == 32 + Q) piv = dkk;
        float c = (i == 32 + Q) ? 0.0f : a2[Q] * __builtin_amdgcn_rcpf(dkk);
        ki_upd2<Q, Q + 1>(a2, c);
        a2[Q] = c;
        ki_a2sweep<Q + 1>(a2, ld, piv, i);
    }
}
template<int J>
__device__ __forceinline__ void g1_init(float (&g)[HN], int i) {
    if constexpr (J < HN) { g[J] = (J == i) ? 1.0f : 0.0f; g1_init<J + 1>(g, i); }
}
template<int K, int J>
__device__ __forceinline__ void g1_updA(float (&g)[HN], float c) {
    if constexpr (J <= K) {
        g[J] = fmaf(-c, bcastf(g[J], K), g[J]);
        g1_updA<K, J + 1>(g, c);
    }
}
template<int K>
__device__ __forceinline__ void g1_phase1(float (&g)[HN], const float (&a1)[HN]) {
    if constexpr (K < HN) {
        g1_updA<K, 0>(g, a1[K]);
        g1_phase1<K + 1>(g, a1);
    }
}
template<int Q, int J>
__device__ __forceinline__ void g1_updB(float (&g)[HN], float c) {
    if constexpr (J < HN) {
        g[J] = fmaf(-c, bcastf(g[J], 32 + Q), g[J]);
        g1_updB<Q, J + 1>(g, c);
    }
}
template<int Q>
__device__ __forceinline__ void g1_phase2(float (&g)[HN], const float (&a2)[HN]) {
    if constexpr (Q < HN) {
        g1_updB<Q, 0>(g, a2[Q]);
        g1_phase2<Q + 1>(g, a2);
    }
}
template<int J>
__device__ __forceinline__ void g2_init(float (&g)[HN], int i) {
    if constexpr (J < HN) { g[J] = (32 + J == i) ? 1.0f : 0.0f; g2_init<J + 1>(g, i); }
}
template<int Q, int J>
__device__ __forceinline__ void g2_upd(float (&g)[HN], float c) {
    if constexpr (J <= Q) {
        g[J] = fmaf(-c, bcastf(g[J], 32 + Q), g[J]);
        g2_upd<Q, J + 1>(g, c);
    }
}
template<int Q>
__device__ __forceinline__ void g2_phase(float (&g)[HN], const float (&a2)[HN]) {
    if constexpr (Q < HN) {
        g2_upd<Q, 0>(g, a2[Q]);
        g2_phase<Q + 1>(g, a2);
    }
}
template<int J>
__device__ __forceinline__ void pan_out(const float (&g)[HN], float rdi,
                                        float* __restrict__ dst) {
    if constexpr (J < HN) {
        dst[J] = g[J] * rdi;
        pan_out<J + 1>(g, rdi, dst);
    }
}

__global__ __launch_bounds__(256)
void k_ll_kinv(const float* __restrict__ X,
               const float* __restrict__ Mn,
               const float* __restrict__ R,
               const float* __restrict__ Kmat,
               float* __restrict__ kinv,
               float* __restrict__ logdetK,
               float* __restrict__ out) {
    if (blockIdx.x < 64) {
        // 2 blocks per latent: both redo the sweeps, split the reconstruction
        if (threadIdx.x >= 64) return;
        const int l = blockIdx.x >> 1;
        const int half = blockIdx.x & 1;
        const int i = threadIdx.x;       // row

        float ld = 0.0f, piv = 1.0f;
        float a1[HN], a2[HN];
        pan_load<0>(a1, Kmat, i, l, 0);
        ki_a1sweep<0>(a1, ld, piv, i);
        pan_load<0>(a2, Kmat, i, l, 32);
        ki_replay<0>(a2, a1);
        ki_a2sweep<0>(a2, ld, piv, i);
        float rdi = __builtin_amdgcn_rcpf(piv);
        if (half == 0) {
            float g1[HN];
            g1_init<0>(g1, i);
            g1_phase1<0>(g1, a1);
            g1_phase2<0>(g1, a2);
            pan_out<0>(g1, rdi, kinv + l * (TN * TN) + i * TN);
        } else {
            float g2[HN];
            g2_init<0>(g2, i);
            g2_phase<0>(g2, a2);
            pan_out<0>(g2, rdi, kinv + l * (TN * TN) + i * TN + 32);
            if (i == 0) logdetK[l] = ld;
        }
        return;
    }

    // ---- log-likelihood block (b,s) ----
    int hw = blockIdx.x - 64;            // 1024 blocks
    int g = (hw & 7) * 128 + (hw >> 3);
    int b = g >> 2, s = g & 3;
    int tid = threadIdx.x;

    const float4* xp = (const float4*)(X + (size_t)b * TN * DN);
    const float4* mp = (const float4*)(Mn + ((size_t)(b * SN + s) * TN) * DN);

    int c = tid & 31;
    float4 rv = ((const float4*)R)[c];
    float4 ri = make_float4(1.0f / rv.x, 1.0f / rv.y, 1.0f / rv.z, 1.0f / rv.w);

    float acc = 0.0f;
#pragma unroll
    for (int it = 0; it < (TN * DN / 4) / 256; ++it) {
        int f = tid + it * 256;
        float4 xv = xp[f];
        float4 mv = mp[f];
        float dx = xv.x - mv.x; acc = fmaf(dx * dx, ri.x, acc);
        float dy = xv.y - mv.y; acc = fmaf(dy * dy, ri.y, acc);
        float dz = xv.z - mv.z; acc = fmaf(dz * dz, ri.z, acc);
        float dw = xv.w - mv.w; acc = fmaf(dw * dw, ri.w, acc);
    }
#pragma unroll
    for (int off = 32; off >= 1; off >>= 1) acc += __shfl_xor(acc, off, 64);

    __shared__ float wsum[4];
    if ((tid & 63) == 0) wsum[tid >> 6] = acc;
    __syncthreads();
    if (tid == 0) {
        float q = wsum[0] + wsum[1] + wsum[2] + wsum[3];
        float val = q * (0.5f / SN);
        if (s == 0) {
            float slr = 0.0f;
#pragma unroll
            for (int d = 0; d < DN; ++d) slr += __logf(R[d]);
            val += 0.5f * (float)TN * (slr + (float)DN * LOG2PI);
        }
        atomicAdd(&out[b], val);
    }
}

// ---------------------------------------------------------------------------
extern "C" void kernel_launch(void* const* d_in, const int* in_sizes, int n_in,
                              void* d_out, int out_size, void* d_ws, size_t ws_size,
                              hipStream_t stream) {
    const float* X   = (const float*)d_in[0];  // [B,T,D]
    const float* Mn  = (const float*)d_in[1];  // [B,S,T,D]
    const float* R   = (const float*)d_in[2];  // [D]
    const float* mus = (const float*)d_in[3];  // [B,T,L]
    const float* Sg  = (const float*)d_in[4];  // [B,T,T,L]
    const float* Km  = (const float*)d_in[5];  // [T,T,L]
    float* out = (float*)d_out;                // [B] fp32

    float* kinv = (float*)d_ws;                // 32*4096 floats = 512 KB
    float* ldK  = kinv + LN * TN * TN;         // 32 floats

    hipMemsetAsync(d_out, 0, BN * sizeof(float), stream);
    k_ll_kinv<<<64 + BN * SN, 256, 0, stream>>>(X, Mn, R, Km, kinv, ldK, out);
    k_chol<<<BN * 8, 256, 0, stream>>>(Sg, mus, kinv, ldK, out);
}